// Round 1
// baseline (101.907 us; speedup 1.0000x reference)
//
#include <hip/hip_runtime.h>
#include <math.h>

#define BN 1024   // batch
#define CN 512    // clusters
#define DN 256    // dims

// ---------------- Kernel 0: s[d] = sqrt(attn[d] / sum(attn)) ----------------
__global__ void prep_kernel(const float* __restrict__ attn, float* __restrict__ s) {
    __shared__ float red[4];
    int t = threadIdx.x;              // 256 threads == DN
    float v = attn[t];
    float x = v;
    #pragma unroll
    for (int off = 32; off > 0; off >>= 1) x += __shfl_xor(x, off);  // 64-lane wave reduce
    if ((t & 63) == 0) red[t >> 6] = x;
    __syncthreads();
    if (t == 0) red[0] = red[0] + red[1] + red[2] + red[3];
    __syncthreads();
    float total = red[0];
    s[t] = sqrtf(v / total);
}

// ---------------- Kernel A: t[b,c] = sqrt( sum_d (s_d*x_bd - s_d*w_cd)^2 ) ----------------
#define TM 64
#define TN 32
#define BK 32
#define TMP 68   // 68*4B = 272B row stride, 16B-aligned, breaks 32-bank pattern
#define TNP 34   // 34*4B = 136B row stride, 8B-aligned

__launch_bounds__(256, 1)
__global__ void dist_kernel(const float* __restrict__ inp, const float* __restrict__ wd,
                            const float* __restrict__ s, float* __restrict__ tout) {
    __shared__ __align__(16) float aT[BK][TMP];
    __shared__ __align__(16) float bT[BK][TNP];

    const int m0 = blockIdx.x * TM;
    const int n0 = blockIdx.y * TN;
    const int tid = threadIdx.x;
    const int tr = tid & 15;    // 16 row-groups
    const int tc = tid >> 4;    // 16 col-groups

    float acc[4][2] = {{0.f, 0.f}, {0.f, 0.f}, {0.f, 0.f}, {0.f, 0.f}};

    for (int k0 = 0; k0 < DN; k0 += BK) {
        // stage A tile (64 rows x 32 k), transposed to k-major, pre-scaled by s[d]
        #pragma unroll
        for (int j = 0; j < 8; ++j) {
            int e = tid + j * 256;
            int row = e >> 5, col = e & 31;
            aT[col][row] = inp[(m0 + row) * DN + k0 + col] * s[k0 + col];
        }
        // stage B tile (32 rows x 32 k)
        #pragma unroll
        for (int j = 0; j < 4; ++j) {
            int e = tid + j * 256;
            int row = e >> 5, col = e & 31;
            bT[col][row] = wd[(n0 + row) * DN + k0 + col] * s[k0 + col];
        }
        __syncthreads();
        #pragma unroll
        for (int k = 0; k < BK; ++k) {
            float4 a = *(const float4*)&aT[k][tr * 4];
            float2 b = *(const float2*)&bT[k][tc * 2];
            float av[4] = {a.x, a.y, a.z, a.w};
            float bv[2] = {b.x, b.y};
            #pragma unroll
            for (int i = 0; i < 4; ++i)
                #pragma unroll
                for (int j = 0; j < 2; ++j) {
                    float d = av[i] - bv[j];
                    acc[i][j] = fmaf(d, d, acc[i][j]);
                }
        }
        __syncthreads();
    }

    #pragma unroll
    for (int i = 0; i < 4; ++i) {
        int row = m0 + tr * 4 + i;
        float2 o;
        o.x = sqrtf(acc[i][0]);
        o.y = sqrtf(acc[i][1]);
        *(float2*)&tout[row * CN + n0 + tc * 2] = o;
    }
}

// ---------------- Kernel B: per-row double softmax + readout ----------------
__device__ __forceinline__ float blockReduceMax(float v, float* red) {
    #pragma unroll
    for (int off = 32; off > 0; off >>= 1) v = fmaxf(v, __shfl_xor(v, off));
    if ((threadIdx.x & 63) == 0) red[threadIdx.x >> 6] = v;
    __syncthreads();
    float r = red[0];
    #pragma unroll
    for (int i = 1; i < 8; ++i) r = fmaxf(r, red[i]);
    __syncthreads();
    return r;
}

__device__ __forceinline__ float blockReduceSum(float v, float* red) {
    #pragma unroll
    for (int off = 32; off > 0; off >>= 1) v += __shfl_xor(v, off);
    if ((threadIdx.x & 63) == 0) red[threadIdx.x >> 6] = v;
    __syncthreads();
    float r = red[0];
    #pragma unroll
    for (int i = 1; i < 8; ++i) r += red[i];
    __syncthreads();
    return r;
}

__launch_bounds__(512, 1)
__global__ void softmax_kernel(const float* __restrict__ tarr, const int* __restrict__ mask,
                               const float* __restrict__ w_assoc, float* __restrict__ y) {
    __shared__ float red[8];
    const int b = blockIdx.x;
    const int c = threadIdx.x;           // 512 threads == CN

    float t = tarr[b * CN + c];
    const bool rec = mask[c] > 0;

    // softmax #1: logits = rec ? -3*t : -1e30   (BETA*log(H)/TEMP_COMP = -3*sqrt(wdist))
    float l1 = rec ? (-3.0f * t) : -1e30f;
    float mx1 = blockReduceMax(l1, red);
    float e1 = rec ? expf(l1 - mx1) : 0.0f;
    float sum1 = blockReduceSum(e1, red);
    float p_comp = e1 / sum1;
    float H = expf(-t);
    float competed = p_comp * H;         // zero for non-recruited (e1 = 0)

    // softmax #2: logits = rec ? competed/0.1 : -1e30
    float l2 = rec ? (competed * 10.0f) : -1e30f;
    float mx2 = blockReduceMax(l2, red);
    float e2 = rec ? expf(l2 - mx2) : 0.0f;
    float sum2 = blockReduceSum(e2, red);
    float p_wta = e2 / sum2;
    float sw = p_wta * competed;

    // readout: y = 1.5 * (softwta @ w_assoc)
    float2 wa = *(const float2*)&w_assoc[c * 2];
    float y0 = blockReduceSum(sw * wa.x, red);
    float y1 = blockReduceSum(sw * wa.y, red);
    if (c == 0) {
        y[b * 2 + 0] = 1.5f * y0;
        y[b * 2 + 1] = 1.5f * y1;
    }
}

extern "C" void kernel_launch(void* const* d_in, const int* in_sizes, int n_in,
                              void* d_out, int out_size, void* d_ws, size_t ws_size,
                              hipStream_t stream) {
    const float* inp     = (const float*)d_in[0];  // [B, D]
    const float* w_dist  = (const float*)d_in[1];  // [C, D]
    const float* attn    = (const float*)d_in[2];  // [D]
    const float* w_assoc = (const float*)d_in[3];  // [C, 2]
    const int*   mask    = (const int*)d_in[4];    // [C]
    float* out = (float*)d_out;                    // [B, 2]

    float* s    = (float*)d_ws;                    // [D] sqrt-normalized attention
    float* tarr = s + DN;                          // [B, C] sqrt(wdist)

    prep_kernel<<<1, DN, 0, stream>>>(attn, s);
    dim3 gA(BN / TM, CN / TN);                     // 16 x 16 = 256 blocks
    dist_kernel<<<gA, 256, 0, stream>>>(inp, w_dist, s, tarr);
    softmax_kernel<<<BN, CN, 0, stream>>>(tarr, mask, w_assoc, out);
}

// Round 3
// 75.594 us; speedup vs baseline: 1.3481x; 1.3481x over previous
//
#include <hip/hip_runtime.h>
#include <math.h>

#define BN 1024   // batch
#define CN 512    // clusters
#define DN 256    // dims
#define NZ 4      // K-split factor
#define KZ (DN / NZ)   // 64 k per block
#define TM 64
#define TN 64

// ---------------------------------------------------------------------------
// dist kernel: pdot[z][b][c] = sum_{d in chunk z} (s_d*x_bd - s_d*w_cd)^2
// grid (BN/TM, CN/TN, NZ) = (16, 8, 4) = 512 blocks, 256 threads, 8 waves/CU.
// Attn normalization folded in (1 KB redundant reduce per block, L2-hot).
// LDS: A/B tiles staged once (K=64 fits), XOR-swizzled k4 ^= row>>2 so the
// 4-row b128 reads are bank-conflict-free (T2 pattern, both-sides swizzle).
// ---------------------------------------------------------------------------
__launch_bounds__(256, 2)
__global__ void dist_kernel(const float* __restrict__ inp, const float* __restrict__ wd,
                            const float* __restrict__ attn, float* __restrict__ pdot) {
    __shared__ __align__(16) float aR[TM * KZ];
    __shared__ __align__(16) float bR[TN * KZ];
    __shared__ __align__(16) float s_lds[KZ];
    __shared__ float red[4];

    const int tid = threadIdx.x;
    const int m0 = blockIdx.x * TM;
    const int n0 = blockIdx.y * TN;
    const int z  = blockIdx.z;
    const int k0 = z * KZ;

    // ---- inline attention normalization: s_d = sqrt(attn_d / sum(attn)) ----
    float av = attn[tid];                      // 256 threads == DN
    float xs = av;
    #pragma unroll
    for (int off = 32; off > 0; off >>= 1) xs += __shfl_xor(xs, off);
    if ((tid & 63) == 0) red[tid >> 6] = xs;
    __syncthreads();
    const float total = red[0] + red[1] + red[2] + red[3];
    if ((tid >> 6) == z) s_lds[tid & 63] = sqrtf(av / total);
    __syncthreads();

    // ---- stage A (64 rows x 64 k) and B (64 rows x 64 k), scaled by s ----
    {
        const int k4   = tid & 15;             // which float4 along k
        const int rbase = tid >> 4;            // 0..15
        const float4 sv = *(const float4*)&s_lds[k4 * 4];
        #pragma unroll
        for (int p = 0; p < 4; ++p) {
            const int row = rbase + 16 * p;
            const int wi  = row * KZ + 4 * (k4 ^ (row >> 2));   // swizzled dest
            float4 a4 = *(const float4*)&inp[(m0 + row) * DN + k0 + 4 * k4];
            a4.x *= sv.x; a4.y *= sv.y; a4.z *= sv.z; a4.w *= sv.w;
            *(float4*)&aR[wi] = a4;
            float4 b4 = *(const float4*)&wd[(n0 + row) * DN + k0 + 4 * k4];
            b4.x *= sv.x; b4.y *= sv.y; b4.z *= sv.z; b4.w *= sv.w;
            *(float4*)&bR[wi] = b4;
        }
    }
    __syncthreads();

    // ---- register-tiled compute: 4x4 outputs/thread ----
    const int tr = tid & 15;                   // row group
    const int tc = tid >> 4;                   // col group
    float acc[4][4] = {};

    #pragma unroll 4
    for (int k4 = 0; k4 < 16; ++k4) {
        float4 a[4], b[4];
        const int ka = 4 * (k4 ^ tr);          // matches store swizzle (row>>2 == tr)
        const int kb = 4 * (k4 ^ tc);
        #pragma unroll
        for (int i = 0; i < 4; ++i) a[i] = *(const float4*)&aR[(4 * tr + i) * KZ + ka];
        #pragma unroll
        for (int j = 0; j < 4; ++j) b[j] = *(const float4*)&bR[(4 * tc + j) * KZ + kb];
        const float* af = (const float*)a;
        const float* bf = (const float*)b;
        #pragma unroll
        for (int kk = 0; kk < 4; ++kk)
            #pragma unroll
            for (int i = 0; i < 4; ++i) {
                const float ai = af[i * 4 + kk];
                #pragma unroll
                for (int j = 0; j < 4; ++j) {
                    const float d = ai - bf[j * 4 + kk];
                    acc[i][j] = fmaf(d, d, acc[i][j]);
                }
            }
    }

    // ---- write partial sums (coalesced float4 per row) ----
    float* po = pdot + (size_t)z * BN * CN;
    #pragma unroll
    for (int i = 0; i < 4; ++i) {
        const int r = m0 + 4 * tr + i;
        float4 o = {acc[i][0], acc[i][1], acc[i][2], acc[i][3]};
        *(float4*)&po[r * CN + n0 + 4 * tc] = o;
    }
}

// ---------------------------------------------------------------------------
// finish kernel: combine partials, t=sqrt(wdist), double softmax, readout.
// One wave per batch row, 8 clusters/lane, shuffle-only reductions.
// grid 256 blocks x 256 threads (4 rows/block).
// ---------------------------------------------------------------------------
#define NEG_INF_F (-1e30f)

__device__ __forceinline__ float waveMax(float v) {
    #pragma unroll
    for (int off = 32; off > 0; off >>= 1) v = fmaxf(v, __shfl_xor(v, off));
    return v;
}
__device__ __forceinline__ float waveSum(float v) {
    #pragma unroll
    for (int off = 32; off > 0; off >>= 1) v += __shfl_xor(v, off);
    return v;
}

__launch_bounds__(256, 2)
__global__ void finish_kernel(const float* __restrict__ pdot, const int* __restrict__ mask,
                              const float* __restrict__ w_assoc, float* __restrict__ y) {
    const int tid  = threadIdx.x;
    const int lane = tid & 63;
    const int b    = blockIdx.x * 4 + (tid >> 6);
    const int cb   = lane * 8;                 // 8 consecutive clusters per lane

    // combine K-split partials and take sqrt
    float t[8];
    #pragma unroll
    for (int q = 0; q < 2; ++q) {
        float4 p = {0.f, 0.f, 0.f, 0.f};
        #pragma unroll
        for (int z = 0; z < 4; ++z) {
            const float4 v = *(const float4*)&pdot[(size_t)z * BN * CN + b * CN + cb + 4 * q];
            p.x += v.x; p.y += v.y; p.z += v.z; p.w += v.w;
        }
        t[4 * q + 0] = sqrtf(p.x); t[4 * q + 1] = sqrtf(p.y);
        t[4 * q + 2] = sqrtf(p.z); t[4 * q + 3] = sqrtf(p.w);
    }

    const int4 m0 = *(const int4*)&mask[cb];
    const int4 m1 = *(const int4*)&mask[cb + 4];
    bool rec[8] = {m0.x > 0, m0.y > 0, m0.z > 0, m0.w > 0,
                   m1.x > 0, m1.y > 0, m1.z > 0, m1.w > 0};

    // softmax #1 over logits -3*t (recruited only)
    float l1[8], lmax = NEG_INF_F;
    #pragma unroll
    for (int j = 0; j < 8; ++j) { l1[j] = rec[j] ? (-3.0f * t[j]) : NEG_INF_F; lmax = fmaxf(lmax, l1[j]); }
    const float mx1 = waveMax(lmax);
    float e1[8], lsum = 0.f;
    #pragma unroll
    for (int j = 0; j < 8; ++j) { e1[j] = rec[j] ? expf(l1[j] - mx1) : 0.f; lsum += e1[j]; }
    const float s1 = waveSum(lsum);
    const float inv_s1 = 1.0f / s1;

    // competed = p_comp * H,  H = exp(-t)
    float competed[8];
    #pragma unroll
    for (int j = 0; j < 8; ++j) competed[j] = e1[j] * inv_s1 * expf(-t[j]);

    // softmax #2 over logits competed/0.1 (recruited only)
    float l2[8]; lmax = NEG_INF_F;
    #pragma unroll
    for (int j = 0; j < 8; ++j) { l2[j] = rec[j] ? (competed[j] * 10.0f) : NEG_INF_F; lmax = fmaxf(lmax, l2[j]); }
    const float mx2 = waveMax(lmax);
    float e2[8]; lsum = 0.f;
    #pragma unroll
    for (int j = 0; j < 8; ++j) { e2[j] = rec[j] ? expf(l2[j] - mx2) : 0.f; lsum += e2[j]; }
    const float s2 = waveSum(lsum);
    const float inv_s2 = 1.0f / s2;

    // readout y = 1.5 * (softwta @ w_assoc)
    float y0 = 0.f, y1 = 0.f;
    #pragma unroll
    for (int q = 0; q < 4; ++q) {
        const float4 wa = *(const float4*)&w_assoc[2 * cb + 4 * q];   // clusters 2q, 2q+1
        const float sw0 = e2[2 * q + 0] * inv_s2 * competed[2 * q + 0];
        const float sw1 = e2[2 * q + 1] * inv_s2 * competed[2 * q + 1];
        y0 = fmaf(sw0, wa.x, y0); y1 = fmaf(sw0, wa.y, y1);
        y0 = fmaf(sw1, wa.z, y0); y1 = fmaf(sw1, wa.w, y1);
    }
    y0 = waveSum(y0);
    y1 = waveSum(y1);
    if (lane == 0) {
        float2 o = {1.5f * y0, 1.5f * y1};
        *(float2*)&y[b * 2] = o;
    }
}

extern "C" void kernel_launch(void* const* d_in, const int* in_sizes, int n_in,
                              void* d_out, int out_size, void* d_ws, size_t ws_size,
                              hipStream_t stream) {
    const float* inp     = (const float*)d_in[0];  // [B, D]
    const float* w_dist  = (const float*)d_in[1];  // [C, D]
    const float* attn    = (const float*)d_in[2];  // [D]
    const float* w_assoc = (const float*)d_in[3];  // [C, 2]
    const int*   mask    = (const int*)d_in[4];    // [C]
    float* out = (float*)d_out;                    // [B, 2]

    float* pdot = (float*)d_ws;                    // [NZ, B, C] partial sq-dists (8 MB)

    dim3 gA(BN / TM, CN / TN, NZ);                 // 16 x 8 x 4 = 512 blocks
    dist_kernel<<<gA, 256, 0, stream>>>(inp, w_dist, attn, pdot);
    finish_kernel<<<BN / 4, 256, 0, stream>>>(pdot, mask, w_assoc, out);
}